// Round 4
// baseline (42.949 us; speedup 1.0000x reference)
//
#include <hip/hip_runtime.h>
#include <math.h>

#define EPS 1e-12f

constexpr int Bn = 64;             // batch
constexpr int Np = 512;            // N == M == 512
constexpr int OSPLIT = 4;          // owner splits per (b, pass)
constexpr int OWN = Np / OSPLIT;   // 128 owners per block (64 pairs, ROW=2)
constexpr int TPB = 512;           // 8 waves; each wave takes one k-eighth
constexpr int KSPLIT = 8;
constexpr int KCH = Np / KSPLIT;   // 64 loop points per thread
constexpr int NBLK = Bn * 2 * OSPLIT;  // 512 blocks

// Each thread owns 2 adjacent owner points (registers) and scans a wave-uniform
// eighth of the 512 opposite points straight from global (wave-uniform address
// -> scalar loads; the 2 MB dataset is L2-resident). 8 k-chunk partials are
// combined in LDS, then sqrt + fixed-order sum -> 1 partial per block. The
// last block (device-scope acq_rel counter) does the deterministic final sum.
__global__ __launch_bounds__(TPB) void chamfer_min_kernel(
        const float* __restrict__ p, const float* __restrict__ q,
        float* __restrict__ partial, unsigned* __restrict__ counter,
        float* __restrict__ outp) {
    const int b    = blockIdx.x;
    const int pass = blockIdx.y;
    const int oc   = blockIdx.z;
    const float* A = (pass == 0) ? p : q;   // owner array (2,Bn,Np,4)
    const float* L = (pass == 0) ? q : p;   // loop array

    const int t  = threadIdx.x;
    const int ot = t & 63;
    const int kh = __builtin_amdgcn_readfirstlane(t >> 6);  // wave-uniform chunk

    const float4* are = (const float4*)(A + (size_t)b * Np * 4);
    const float4* aim = (const float4*)(A + (size_t)(Bn + b) * Np * 4);
    const int o = oc * OWN + ot * 2;
    const float4 pr0 = are[o], pr1 = are[o + 1];
    const float4 pi0 = aim[o], pi1 = aim[o + 1];

    const float4* lre = (const float4*)(L + (size_t)b * Np * 4);
    const float4* lim = (const float4*)(L + (size_t)(Bn + b) * Np * 4);

    float s0 = 3.4e38f, s1 = 3.4e38f;
    const int k0 = kh * KCH;
    #pragma unroll 8
    for (int k = k0; k < k0 + KCH; ++k) {
        const float4 qr = lre[k];           // wave-uniform address -> s_load
        const float4 qi = lim[k];
        {
            float drx = pr0.x - qr.x, dry = pr0.y - qr.y;
            float drz = pr0.z - qr.z, drw = pr0.w - qr.w;
            float dix = pi0.x - qi.x, diy = pi0.y - qi.y;
            float diz = pi0.z - qi.z, diw = pi0.w - qi.w;
            float mr  = drx*drx - dry*dry - drz*drz - drw*drw;
            float mi  = drx*dix - dry*diy - drz*diz - drw*diw;
            float mi2 = mi + mi;
            s0 = fminf(s0, mr*mr + mi2*mi2);
        }
        {
            float drx = pr1.x - qr.x, dry = pr1.y - qr.y;
            float drz = pr1.z - qr.z, drw = pr1.w - qr.w;
            float dix = pi1.x - qi.x, diy = pi1.y - qi.y;
            float diz = pi1.z - qi.z, diw = pi1.w - qi.w;
            float mr  = drx*drx - dry*dry - drz*drz - drw*drw;
            float mi  = drx*dix - dry*diy - drz*diz - drw*diw;
            float mi2 = mi + mi;
            s1 = fminf(s1, mr*mr + mi2*mi2);
        }
    }

    __shared__ float2 sred[TPB];
    __shared__ float  red[TPB];
    __shared__ int    sflag;
    sred[t] = make_float2(s0, s1);
    __syncthreads();

    if (t < 64) {
        float m0 = s0, m1 = s1;   // kh==0 lanes already hold their own chunk
        #pragma unroll
        for (int w = 1; w < KSPLIT; ++w) {
            float2 v = sred[t + w * 64];
            m0 = fminf(m0, v.x);
            m1 = fminf(m1, v.y);
        }
        float v = sqrtf(m0 + EPS) + sqrtf(m1 + EPS);
        #pragma unroll
        for (int off = 32; off > 0; off >>= 1)
            v += __shfl_down(v, off, 64);
        if (t == 0) {
            const int bid = (oc * 2 + pass) * Bn + b;
            partial[bid] = v;
            __threadfence();
            unsigned old = __hip_atomic_fetch_add(counter, 1u,
                              __ATOMIC_ACQ_REL, __HIP_MEMORY_SCOPE_AGENT);
            sflag = (old == NBLK - 1) ? 1 : 0;
        }
    }
    __syncthreads();

    if (sflag) {                   // last block: deterministic final sum
        __threadfence();           // agent acquire (belt and braces for L1)
        red[t] = partial[t];       // t in [0,512): all partials
        __syncthreads();
        for (int s = TPB / 2; s > 0; s >>= 1) {
            if (t < s) red[t] += red[t + s];
            __syncthreads();
        }
        if (t == 0) outp[0] = red[0];
    }
}

extern "C" void kernel_launch(void* const* d_in, const int* in_sizes, int n_in,
                              void* d_out, int out_size, void* d_ws, size_t ws_size,
                              hipStream_t stream) {
    const float* p = (const float*)d_in[0];   // (2, 64, 512, 4) fp32
    const float* q = (const float*)d_in[1];   // (2, 64, 512, 4) fp32
    float* out       = (float*)d_out;
    float* partial   = (float*)d_ws;                  // 512 floats
    unsigned* counter = (unsigned*)((char*)d_ws + NBLK * sizeof(float));

    hipMemsetAsync(counter, 0, sizeof(unsigned), stream);   // graph-capturable
    dim3 grid(Bn, 2, OSPLIT);                 // 64 x 2 x 4 = 512 blocks
    chamfer_min_kernel<<<grid, TPB, 0, stream>>>(p, q, partial, counter, out);
}

// Round 5
// 21.368 us; speedup vs baseline: 2.0099x; 2.0099x over previous
//
#include <hip/hip_runtime.h>
#include <math.h>

#define EPS 1e-12f

typedef float v2f __attribute__((ext_vector_type(2)));

constexpr int Bn = 64;             // batch
constexpr int Np = 512;            // N == M == 512
constexpr int OSPLIT = 4;          // owner splits per (b, pass)
constexpr int OWN = Np / OSPLIT;   // 128 owners per block (64 lane-pairs, ROW=2)
constexpr int TPB = 512;           // 8 waves; each wave takes one k-eighth
constexpr int KSPLIT = 8;
constexpr int KCH = Np / KSPLIT;   // 64 loop points per thread

// Each lane owns 2 adjacent owner points, packed into float2 lanes so the
// identical owner0/owner1 op chains become VOP3P packed-fp32 (v_pk_fma_f32
// etc.) -> ~2x VALU instruction throughput. Loop points are read with a
// wave-uniform index straight from global (s_load_dwordx4; 2 MB dataset is
// L2-resident). 8 k-chunk partial mins combine in LDS, then sqrt +
// fixed-order sum -> 1 partial per block; tiny kernel 2 does the final 512-sum.
__global__ __launch_bounds__(TPB) void chamfer_min_kernel(
        const float* __restrict__ p, const float* __restrict__ q,
        float* __restrict__ partial) {
    const int b    = blockIdx.x;
    const int pass = blockIdx.y;
    const int oc   = blockIdx.z;
    const float* A = (pass == 0) ? p : q;   // owner array (2,Bn,Np,4)
    const float* L = (pass == 0) ? q : p;   // loop array

    const int t  = threadIdx.x;
    const int ot = t & 63;
    const int kh = __builtin_amdgcn_readfirstlane(t >> 6);  // wave-uniform chunk

    const float4* are = (const float4*)(A + (size_t)b * Np * 4);
    const float4* aim = (const float4*)(A + (size_t)(Bn + b) * Np * 4);
    const int o = oc * OWN + ot * 2;
    const float4 a0 = are[o], a1 = are[o + 1];
    const float4 b0 = aim[o], b1 = aim[o + 1];
    const v2f prx = {a0.x, a1.x}, pry = {a0.y, a1.y};
    const v2f prz = {a0.z, a1.z}, prw = {a0.w, a1.w};
    const v2f pix = {b0.x, b1.x}, piy = {b0.y, b1.y};
    const v2f piz = {b0.z, b1.z}, piw = {b0.w, b1.w};

    const float4* lre = (const float4*)(L + (size_t)b * Np * 4);
    const float4* lim = (const float4*)(L + (size_t)(Bn + b) * Np * 4);

    v2f smin = {3.4e38f, 3.4e38f};
    const int k0 = kh * KCH;
    #pragma unroll 8
    for (int k = k0; k < k0 + KCH; ++k) {
        const float4 qr = lre[k];           // wave-uniform -> s_load_dwordx4
        const float4 qi = lim[k];
        v2f drx = prx - qr.x, dry = pry - qr.y;
        v2f drz = prz - qr.z, drw = prw - qr.w;
        v2f dix = pix - qi.x, diy = piy - qi.y;
        v2f diz = piz - qi.z, diw = piw - qi.w;
        v2f mr  = drx*drx - dry*dry - drz*drz - drw*drw;
        v2f mi  = drx*dix - dry*diy - drz*diz - drw*diw;
        v2f mi2 = mi + mi;
        v2f s   = mr*mr + mi2*mi2;
        smin = __builtin_elementwise_min(smin, s);
    }

    __shared__ v2f sred[TPB];
    sred[t] = smin;
    __syncthreads();

    if (t < 64) {
        v2f m = smin;                      // kh==0 lanes hold their own chunk
        #pragma unroll
        for (int w = 1; w < KSPLIT; ++w)
            m = __builtin_elementwise_min(m, sred[t + w * 64]);
        float v = sqrtf(m.x + EPS) + sqrtf(m.y + EPS);
        #pragma unroll
        for (int off = 32; off > 0; off >>= 1)
            v += __shfl_down(v, off, 64);
        if (t == 0)
            partial[(((size_t)pass * Bn + b) * OSPLIT) + oc] = v;
    }
}

// Deterministic fixed-order sum of the 512 block partials.
__global__ __launch_bounds__(256) void final_sum_kernel(
        const float* __restrict__ partial, float* __restrict__ outp) {
    __shared__ float red[256];
    const int t = threadIdx.x;
    red[t] = partial[t] + partial[t + 256];
    __syncthreads();
    for (int s = 128; s > 0; s >>= 1) {
        if (t < s) red[t] += red[t + s];
        __syncthreads();
    }
    if (t == 0) outp[0] = red[0];
}

extern "C" void kernel_launch(void* const* d_in, const int* in_sizes, int n_in,
                              void* d_out, int out_size, void* d_ws, size_t ws_size,
                              hipStream_t stream) {
    const float* p = (const float*)d_in[0];   // (2, 64, 512, 4) fp32
    const float* q = (const float*)d_in[1];   // (2, 64, 512, 4) fp32
    float* out     = (float*)d_out;
    float* partial = (float*)d_ws;            // 512 floats

    dim3 grid(Bn, 2, OSPLIT);                 // 64 x 2 x 4 = 512 blocks
    chamfer_min_kernel<<<grid, TPB, 0, stream>>>(p, q, partial);
    final_sum_kernel<<<1, 256, 0, stream>>>(partial, out);
}